// Round 6
// baseline (398.625 us; speedup 1.0000x reference)
//
#include <hip/hip_runtime.h>
#include <cstddef>

// Problem: B=4, C=256, H=W=128, HW=16384, NPIX=65536
#define EPS_ 1e-5f

typedef __attribute__((ext_vector_type(8))) short s16x8;
typedef __attribute__((ext_vector_type(4))) short s16x4;
typedef __attribute__((ext_vector_type(4))) float f32x4;

__device__ __forceinline__ unsigned short f2bf(float f) {
  unsigned u = __builtin_bit_cast(unsigned, f);
  return (unsigned short)((u + 0x7fffu + ((u >> 16) & 1u)) >> 16);   // RNE
}
__device__ __forceinline__ float bf2f(unsigned short h) {
  return __builtin_bit_cast(float, ((unsigned)h) << 16);
}

// ---------------------------------------------------------------------------
// Kernel 0: pre-convert W1 into MFMA B-fragment layout, hi/lo bf16 split.
// ---------------------------------------------------------------------------
__global__ __launch_bounds__(256) void k_wprep(const float* __restrict__ W1,
                                               short* __restrict__ whiF,
                                               short* __restrict__ wloF)
{
  const int tid = blockIdx.x * 256 + threadIdx.x;   // 0..8191
  const int k  = tid >> 10;
  const int n  = (tid >> 6) & 15;
  const int l  = tid & 63;
  const int o  = n * 16 + (l & 15);
  const int cb = k * 32 + ((l >> 4) << 3);
  const float* src = W1 + o * 256 + cb;
  s16x8 hv, lv;
#pragma unroll
  for (int j = 0; j < 8; ++j) {
    const float v = src[j];
    const unsigned short hb = f2bf(v);
    hv[j] = (short)hb;
    lv[j] = (short)f2bf(v - bf2f(hb));
  }
  *(s16x8*)(whiF + (size_t)tid * 8) = hv;
  *(s16x8*)(wloF + (size_t)tid * 8) = lv;
}

// ---------------------------------------------------------------------------
// Kernel 1: GEMM via bf16 MFMA with 2-term split (3 mfma per K-chunk pair).
//   f1[b][o][p] = sum_c x[b][c][p] * W1[o][c] + b1[o]
// (Verified R5: total -65.7us vs fp32 VALU GEMM, absmax 0.0156 passed.)
// ---------------------------------------------------------------------------
#define RS 36
__global__ __launch_bounds__(256, 2) void k_mm(const float* __restrict__ x,
                                               const short* __restrict__ whiF,
                                               const short* __restrict__ wloF,
                                               const float* __restrict__ b1,
                                               float* __restrict__ f1)
{
  __shared__ short lds[2][2][128][RS];   // [dbuf][hi/lo][p][c]  36864 B
  const int tid  = threadIdx.x;
  const int lane = tid & 63;
  const int wid  = tid >> 6;
  const int wp   = wid & 1;
  const int wo   = wid >> 1;
  const int l15  = lane & 15, lg = lane >> 4;
  const int hw0  = blockIdx.x * 128;
  const int b    = blockIdx.y;
  const float* xb = x + ((size_t)b << 22) + hw0;

  const int ps = tid & 127;
  const int cg = tid >> 7;

  f32x4 acc[4][8];
#pragma unroll
  for (int of = 0; of < 8; ++of) {
    const float bias = b1[wo * 128 + of * 16 + l15];
#pragma unroll
    for (int pf = 0; pf < 4; ++pf) {
      acc[pf][of][0] = bias; acc[pf][of][1] = bias;
      acc[pf][of][2] = bias; acc[pf][of][3] = bias;
    }
  }

  float xr[16];
#pragma unroll
  for (int j = 0; j < 16; ++j)
    xr[j] = xb[(size_t)(cg * 16 + j) * 16384 + ps];

  for (int k = 0; k < 8; ++k) {
    const int bk = k & 1;
#pragma unroll
    for (int a = 0; a < 4; ++a) {
      s16x4 hv, lv;
#pragma unroll
      for (int j = 0; j < 4; ++j) {
        const float v = xr[a * 4 + j];
        const unsigned short hb = f2bf(v);
        hv[j] = (short)hb;
        lv[j] = (short)f2bf(v - bf2f(hb));
      }
      *(s16x4*)&lds[bk][0][ps][cg * 16 + a * 4] = hv;
      *(s16x4*)&lds[bk][1][ps][cg * 16 + a * 4] = lv;
    }
    __syncthreads();

    if (k < 7) {
#pragma unroll
      for (int j = 0; j < 16; ++j)
        xr[j] = xb[(size_t)((k + 1) * 32 + cg * 16 + j) * 16384 + ps];
    }

    s16x8 Ah[4], Al[4];
    const int coff = lg << 3;
#pragma unroll
    for (int pf = 0; pf < 4; ++pf) {
      const int row = wp * 64 + pf * 16 + l15;
      s16x4 h0 = *(const s16x4*)&lds[bk][0][row][coff];
      s16x4 h1 = *(const s16x4*)&lds[bk][0][row][coff + 4];
      s16x4 l0 = *(const s16x4*)&lds[bk][1][row][coff];
      s16x4 l1 = *(const s16x4*)&lds[bk][1][row][coff + 4];
      Ah[pf] = __builtin_shufflevector(h0, h1, 0, 1, 2, 3, 4, 5, 6, 7);
      Al[pf] = __builtin_shufflevector(l0, l1, 0, 1, 2, 3, 4, 5, 6, 7);
    }

    const short* wh = whiF + ((size_t)(k * 16 + wo * 8) * 64 + lane) * 8;
    const short* wl = wloF + ((size_t)(k * 16 + wo * 8) * 64 + lane) * 8;
    s16x8 Bh = *(const s16x8*)wh;
    s16x8 Bl = *(const s16x8*)wl;
#pragma unroll
    for (int of = 0; of < 8; ++of) {
      s16x8 nBh = Bh, nBl = Bl;
      if (of < 7) {
        nBh = *(const s16x8*)(wh + (size_t)(of + 1) * 512);
        nBl = *(const s16x8*)(wl + (size_t)(of + 1) * 512);
      }
#pragma unroll
      for (int pf = 0; pf < 4; ++pf) {
        acc[pf][of] = __builtin_amdgcn_mfma_f32_16x16x32_bf16(Ah[pf], Bh, acc[pf][of], 0, 0, 0);
        acc[pf][of] = __builtin_amdgcn_mfma_f32_16x16x32_bf16(Ah[pf], Bl, acc[pf][of], 0, 0, 0);
        acc[pf][of] = __builtin_amdgcn_mfma_f32_16x16x32_bf16(Al[pf], Bh, acc[pf][of], 0, 0, 0);
      }
      Bh = nBh; Bl = nBl;
    }
  }

  float* fb = f1 + ((size_t)b << 22) + hw0;
  const int prow = wp * 64 + (lg << 2);
#pragma unroll
  for (int of = 0; of < 8; ++of) {
    const int o = wo * 128 + of * 16 + l15;
    float* fo = fb + ((size_t)o << 14);
#pragma unroll
    for (int pf = 0; pf < 4; ++pf)
      *(f32x4*)(fo + prow + pf * 16) = acc[pf][of];
  }
}

// ---------------------------------------------------------------------------
// Kernel 2: partial L1 distances. NO atomics: each c-chunk block streams its
// partials to a private slice dist_part[chunk][k][p].
// Grid: (16 htiles, 4 b, 8 c-chunks) = 512 blocks, 256 thr.
// ---------------------------------------------------------------------------
__global__ __launch_bounds__(256) void k_dist(const float* __restrict__ f1,
                                              float* __restrict__ dist_part)
{
  const int t    = threadIdx.x;
  const int r    = t >> 5, cq = t & 31;
  const int lane = t & 63;
  const int h0 = blockIdx.x * 8;
  const int b  = blockIdx.y;
  const int c0 = blockIdx.z * 32;
  const int h  = h0 + r;
  const int hu = h == 0 ? 0 : h - 1;
  const int hd = h == 127 ? 127 : h + 1;
  const int colo = cq * 4;
  const float* plane0 = f1 + ((size_t)(b * 256 + c0)) * 16384;

  float acc[4][8];
#pragma unroll
  for (int i = 0; i < 4; ++i)
#pragma unroll
    for (int k = 0; k < 8; ++k) acc[i][k] = 0.f;

#pragma unroll 4
  for (int cc = 0; cc < 32; ++cc) {
    const float* pl = plane0 + (size_t)cc * 16384;
    float4 vv[3];
    vv[0] = *(const float4*)(pl + hu * 128 + colo);
    vv[1] = *(const float4*)(pl + h  * 128 + colo);
    vv[2] = *(const float4*)(pl + hd * 128 + colo);
    float vals[3][6];
#pragma unroll
    for (int d = 0; d < 3; ++d) {
      const float lf = __shfl(vv[d].w, (lane + 63) & 63, 64);
      const float rg = __shfl(vv[d].x, (lane + 1) & 63, 64);
      vals[d][0] = (cq == 0)  ? vv[d].x : lf;
      vals[d][1] = vv[d].x; vals[d][2] = vv[d].y;
      vals[d][3] = vv[d].z; vals[d][4] = vv[d].w;
      vals[d][5] = (cq == 31) ? vv[d].w : rg;
    }
#pragma unroll
    for (int i = 0; i < 4; ++i) {
      const float cv = vals[1][i + 1];
      acc[i][0] += fabsf(cv - vals[0][i]);
      acc[i][1] += fabsf(cv - vals[0][i + 1]);
      acc[i][2] += fabsf(cv - vals[0][i + 2]);
      acc[i][3] += fabsf(cv - vals[1][i]);
      acc[i][4] += fabsf(cv - vals[1][i + 2]);
      acc[i][5] += fabsf(cv - vals[2][i]);
      acc[i][6] += fabsf(cv - vals[2][i + 1]);
      acc[i][7] += fabsf(cv - vals[2][i + 2]);
    }
  }

  const int p = (b << 14) + h * 128 + colo;
  float* base = dist_part + ((size_t)blockIdx.z << 19);   // chunk * 8*65536
#pragma unroll
  for (int k = 0; k < 8; ++k) {
    float4 v; v.x = acc[0][k]; v.y = acc[1][k]; v.z = acc[2][k]; v.w = acc[3][k];
    *(float4*)(base + (size_t)k * 65536 + p) = v;
  }
}

// ---------------------------------------------------------------------------
// Kernel 2b: sum the 8 chunk-partials per pixel, softmax once, write wts[p][8].
// ---------------------------------------------------------------------------
__global__ __launch_bounds__(256) void k_soft(const float* __restrict__ dist_part,
                                              const float* __restrict__ rp,
                                              float* __restrict__ wts)
{
  const int p = blockIdx.x * 256 + threadIdx.x;
  const float rv = rp[0];
  float d[8];
#pragma unroll
  for (int k = 0; k < 8; ++k) d[k] = 0.f;
  for (int ch = 0; ch < 8; ++ch) {
    const float* base = dist_part + ((size_t)ch << 19);
#pragma unroll
    for (int k = 0; k < 8; ++k) d[k] += base[(size_t)k * 65536 + p];
  }
  float lg[8];
  float mx = -rv * d[0];
#pragma unroll
  for (int k = 1; k < 8; ++k) mx = fmaxf(mx, -rv * d[k]);
  float sm = 0.f;
#pragma unroll
  for (int k = 0; k < 8; ++k) { lg[k] = __expf(fmaf(-rv, d[k], -mx)); sm += lg[k]; }
  const float inv = 1.f / sm;
  float4 w0, w1;
  w0.x = lg[0] * inv; w0.y = lg[1] * inv; w0.z = lg[2] * inv; w0.w = lg[3] * inv;
  w1.x = lg[4] * inv; w1.y = lg[5] * inv; w1.z = lg[6] * inv; w1.w = lg[7] * inv;
  *(float4*)(wts + (size_t)p * 8)     = w0;
  *(float4*)(wts + (size_t)p * 8 + 4) = w1;
}

// ---------------------------------------------------------------------------
// Kernel 3: weighted aggregation + residual + fused BN stats.
// R6 restructure (was 116us: Occ 18%, VALU 7%, HBM 16% -> latency-bound):
//  * grid z 8 chunks x32ch -> 32 chunks x8ch: 512 -> 2048 blocks,
//    occupancy cap 25% -> 100% (total atomics unchanged).
//  * butterfly reduction DEFERRED out of the cc loop: per-thread ss[8]/qq[8]
//    (statically indexed via full unroll), 16 independent shuffle chains at
//    block end instead of a 12-op serial chain inside every iteration.
// ---------------------------------------------------------------------------
__global__ __launch_bounds__(256, 4) void k_agg2(const float* __restrict__ f1,
                                                 const float* __restrict__ x,
                                                 const float* __restrict__ wts,
                                                 float* __restrict__ bn_in,
                                                 float* __restrict__ s1,
                                                 float* __restrict__ s2)
{
  const int t    = threadIdx.x;
  const int r    = t >> 5, cq = t & 31;
  const int lane = t & 63;
  const int h0 = blockIdx.x * 8;
  const int b  = blockIdx.y;
  const int c0 = blockIdx.z * 8;          // 8 channels per block now
  const int h  = h0 + r;
  const int hu = h == 0 ? 0 : h - 1;
  const int hd = h == 127 ? 127 : h + 1;
  const int colo = cq * 4;
  const int p  = (b << 14) + h * 128 + colo;

  float m[4][8];
#pragma unroll
  for (int i = 0; i < 4; ++i) {
    float4 w0 = *(const float4*)(wts + (size_t)(p + i) * 8);
    float4 w1 = *(const float4*)(wts + (size_t)(p + i) * 8 + 4);
    m[i][0] = w0.x; m[i][1] = w0.y; m[i][2] = w0.z; m[i][3] = w0.w;
    m[i][4] = w1.x; m[i][5] = w1.y; m[i][6] = w1.z; m[i][7] = w1.w;
  }

  const float* plane0 = f1 + ((size_t)(b * 256 + c0)) * 16384;
  float ss[8], qq[8];

#pragma unroll
  for (int cc = 0; cc < 8; ++cc) {
    const float* pl = plane0 + (size_t)cc * 16384;
    float4 vv[3];
    vv[0] = *(const float4*)(pl + hu * 128 + colo);
    vv[1] = *(const float4*)(pl + h  * 128 + colo);
    vv[2] = *(const float4*)(pl + hd * 128 + colo);
    float vals[3][6];
#pragma unroll
    for (int d = 0; d < 3; ++d) {
      const float lf = __shfl(vv[d].w, (lane + 63) & 63, 64);
      const float rg = __shfl(vv[d].x, (lane + 1) & 63, 64);
      vals[d][0] = (cq == 0)  ? vv[d].x : lf;
      vals[d][1] = vv[d].x; vals[d][2] = vv[d].y;
      vals[d][3] = vv[d].z; vals[d][4] = vv[d].w;
      vals[d][5] = (cq == 31) ? vv[d].w : rg;
    }

    const size_t chanoff = ((size_t)(b * 256 + c0 + cc)) * 16384 +
                           (size_t)h * 128 + colo;
    const float4 xv = *(const float4*)(x + chanoff);
    float o_[4] = {xv.x, xv.y, xv.z, xv.w};
#pragma unroll
    for (int i = 0; i < 4; ++i) {
      o_[i] = fmaf(m[i][0], vals[0][i],     o_[i]);
      o_[i] = fmaf(m[i][1], vals[0][i + 1], o_[i]);
      o_[i] = fmaf(m[i][2], vals[0][i + 2], o_[i]);
      o_[i] = fmaf(m[i][3], vals[1][i],     o_[i]);
      o_[i] = fmaf(m[i][4], vals[1][i + 2], o_[i]);
      o_[i] = fmaf(m[i][5], vals[2][i],     o_[i]);
      o_[i] = fmaf(m[i][6], vals[2][i + 1], o_[i]);
      o_[i] = fmaf(m[i][7], vals[2][i + 2], o_[i]);
    }
    float4 ov; ov.x = o_[0]; ov.y = o_[1]; ov.z = o_[2]; ov.w = o_[3];
    *(float4*)(bn_in + chanoff) = ov;

    ss[cc] = o_[0] + o_[1] + o_[2] + o_[3];
    qq[cc] = o_[0] * o_[0] + o_[1] * o_[1] + o_[2] * o_[2] + o_[3] * o_[3];
  }

  // deferred butterflies: 16 independent chains, fully overlapped
#pragma unroll
  for (int cc = 0; cc < 8; ++cc) {
#pragma unroll
    for (int msk = 1; msk < 64; msk <<= 1) {
      ss[cc] += __shfl_xor(ss[cc], msk, 64);
      qq[cc] += __shfl_xor(qq[cc], msk, 64);
    }
  }
  if (lane == 0) {
#pragma unroll
    for (int cc = 0; cc < 8; ++cc) {
      atomicAdd(&s1[c0 + cc], ss[cc]);
      atomicAdd(&s2[c0 + cc], qq[cc]);
    }
  }
}

// ---------------------------------------------------------------------------
// Kernel 4: BN folds
// ---------------------------------------------------------------------------
__global__ void k_stats(const float* __restrict__ s1, const float* __restrict__ s2,
                        const float* __restrict__ gamma, const float* __restrict__ beta,
                        float* __restrict__ scale, float* __restrict__ shift)
{
  const int c = threadIdx.x;
  const float n = 65536.f;
  const float mean = s1[c] / n;
  const float var  = s2[c] / n - mean * mean;
  const float sc   = gamma[c] * rsqrtf(var + EPS_);
  scale[c] = sc;
  shift[c] = beta[c] - mean * sc;
}

// ---------------------------------------------------------------------------
// Kernel 5: elementwise BN affine + LeakyReLU
// ---------------------------------------------------------------------------
__global__ __launch_bounds__(256) void k_apply(const float* __restrict__ bn_in,
                                               const float* __restrict__ scale,
                                               const float* __restrict__ shift,
                                               float* __restrict__ out)
{
  const int base = blockIdx.x * 1024 + threadIdx.x;   // float4 index
#pragma unroll
  for (int j = 0; j < 4; ++j) {
    const int idx = base + j * 256;
    const int c   = (idx >> 12) & 255;
    const float sc = scale[c], sh = shift[c];
    const float4 v = *(const float4*)(bn_in + (size_t)idx * 4);
    float4 o;
    float u;
    u = fmaf(v.x, sc, sh); o.x = u > 0.f ? u : 0.01f * u;
    u = fmaf(v.y, sc, sh); o.y = u > 0.f ? u : 0.01f * u;
    u = fmaf(v.z, sc, sh); o.z = u > 0.f ? u : 0.01f * u;
    u = fmaf(v.w, sc, sh); o.w = u > 0.f ? u : 0.01f * u;
    *(float4*)(out + (size_t)idx * 4) = o;
  }
}

// ---------------------------------------------------------------------------
// Workspace: f1 64MB | bn_in 64MB (dist_part 16MB aliases its head; wfrag
// 256KB parks at bn_in+32MB -- both dead before k_agg2 writes) | wts 2MB |
// s1/s2/scale/shift 4KB.  Total ~130MB (unchanged).
// ---------------------------------------------------------------------------
extern "C" void kernel_launch(void* const* d_in, const int* in_sizes, int n_in,
                              void* d_out, int out_size, void* d_ws, size_t ws_size,
                              hipStream_t stream)
{
  const float* x     = (const float*)d_in[0];
  const float* W1    = (const float*)d_in[1];
  const float* b1    = (const float*)d_in[2];
  const float* r     = (const float*)d_in[3];
  const float* gamma = (const float*)d_in[4];
  const float* beta  = (const float*)d_in[5];
  float* out = (float*)d_out;

  char* ws = (char*)d_ws;
  float* f1        = (float*)ws;                           // 64 MB
  float* bn_in     = (float*)(ws + ((size_t)64 << 20));    // 64 MB
  float* dist_part = bn_in;                                // 16 MB alias (dead before bn_in written)
  short* whiF      = (short*)(ws + ((size_t)96 << 20));    // 128 KB (inside bn_in, dead region)
  short* wloF      = whiF + 65536;                         // 128 KB
  float* wts       = (float*)(ws + ((size_t)128 << 20));   // 2 MB
  float* s1        = wts + 524288;
  float* s2        = s1 + 256;
  float* scale     = s1 + 512;
  float* shift     = s1 + 768;

  hipMemsetAsync(s1, 0, 512 * sizeof(float), stream);

  k_wprep<<<dim3(32),        256, 0, stream>>>(W1, whiF, wloF);
  k_mm   <<<dim3(128, 4),    256, 0, stream>>>(x, whiF, wloF, b1, f1);
  k_dist <<<dim3(16, 4, 8),  256, 0, stream>>>(f1, dist_part);
  k_soft <<<dim3(256),       256, 0, stream>>>(dist_part, r, wts);
  k_agg2 <<<dim3(16, 4, 32), 256, 0, stream>>>(f1, x, wts, bn_in, s1, s2);
  k_stats<<<dim3(1),         256, 0, stream>>>(s1, s2, gamma, beta, scale, shift);
  k_apply<<<dim3(4096),      256, 0, stream>>>(bn_in, scale, shift, out);
}

// Round 7
// 345.495 us; speedup vs baseline: 1.1538x; 1.1538x over previous
//
#include <hip/hip_runtime.h>
#include <cstddef>

// Problem: B=4, C=256, H=W=128, HW=16384, NPIX=65536
#define EPS_ 1e-5f

typedef __attribute__((ext_vector_type(8))) short s16x8;
typedef __attribute__((ext_vector_type(4))) short s16x4;
typedef __attribute__((ext_vector_type(4))) float f32x4;

__device__ __forceinline__ unsigned short f2bf(float f) {
  unsigned u = __builtin_bit_cast(unsigned, f);
  return (unsigned short)((u + 0x7fffu + ((u >> 16) & 1u)) >> 16);   // RNE
}
__device__ __forceinline__ float bf2f(unsigned short h) {
  return __builtin_bit_cast(float, ((unsigned)h) << 16);
}

// ---------------------------------------------------------------------------
// Kernel 0: pre-convert W1 into MFMA B-fragment layout, hi/lo bf16 split.
// ---------------------------------------------------------------------------
__global__ __launch_bounds__(256) void k_wprep(const float* __restrict__ W1,
                                               short* __restrict__ whiF,
                                               short* __restrict__ wloF)
{
  const int tid = blockIdx.x * 256 + threadIdx.x;   // 0..8191
  const int k  = tid >> 10;
  const int n  = (tid >> 6) & 15;
  const int l  = tid & 63;
  const int o  = n * 16 + (l & 15);
  const int cb = k * 32 + ((l >> 4) << 3);
  const float* src = W1 + o * 256 + cb;
  s16x8 hv, lv;
#pragma unroll
  for (int j = 0; j < 8; ++j) {
    const float v = src[j];
    const unsigned short hb = f2bf(v);
    hv[j] = (short)hb;
    lv[j] = (short)f2bf(v - bf2f(hb));
  }
  *(s16x8*)(whiF + (size_t)tid * 8) = hv;
  *(s16x8*)(wloF + (size_t)tid * 8) = lv;
}

// ---------------------------------------------------------------------------
// Kernel 1: GEMM via bf16 MFMA with 2-term split (3 mfma per K-chunk pair).
// (Verified R5: total -65.7us vs fp32 VALU GEMM, absmax 0.0156 passed.)
// ---------------------------------------------------------------------------
#define RS 36
__global__ __launch_bounds__(256, 2) void k_mm(const float* __restrict__ x,
                                               const short* __restrict__ whiF,
                                               const short* __restrict__ wloF,
                                               const float* __restrict__ b1,
                                               float* __restrict__ f1)
{
  __shared__ short lds[2][2][128][RS];   // [dbuf][hi/lo][p][c]  36864 B
  const int tid  = threadIdx.x;
  const int lane = tid & 63;
  const int wid  = tid >> 6;
  const int wp   = wid & 1;
  const int wo   = wid >> 1;
  const int l15  = lane & 15, lg = lane >> 4;
  const int hw0  = blockIdx.x * 128;
  const int b    = blockIdx.y;
  const float* xb = x + ((size_t)b << 22) + hw0;

  const int ps = tid & 127;
  const int cg = tid >> 7;

  f32x4 acc[4][8];
#pragma unroll
  for (int of = 0; of < 8; ++of) {
    const float bias = b1[wo * 128 + of * 16 + l15];
#pragma unroll
    for (int pf = 0; pf < 4; ++pf) {
      acc[pf][of][0] = bias; acc[pf][of][1] = bias;
      acc[pf][of][2] = bias; acc[pf][of][3] = bias;
    }
  }

  float xr[16];
#pragma unroll
  for (int j = 0; j < 16; ++j)
    xr[j] = xb[(size_t)(cg * 16 + j) * 16384 + ps];

  for (int k = 0; k < 8; ++k) {
    const int bk = k & 1;
#pragma unroll
    for (int a = 0; a < 4; ++a) {
      s16x4 hv, lv;
#pragma unroll
      for (int j = 0; j < 4; ++j) {
        const float v = xr[a * 4 + j];
        const unsigned short hb = f2bf(v);
        hv[j] = (short)hb;
        lv[j] = (short)f2bf(v - bf2f(hb));
      }
      *(s16x4*)&lds[bk][0][ps][cg * 16 + a * 4] = hv;
      *(s16x4*)&lds[bk][1][ps][cg * 16 + a * 4] = lv;
    }
    __syncthreads();

    if (k < 7) {
#pragma unroll
      for (int j = 0; j < 16; ++j)
        xr[j] = xb[(size_t)((k + 1) * 32 + cg * 16 + j) * 16384 + ps];
    }

    s16x8 Ah[4], Al[4];
    const int coff = lg << 3;
#pragma unroll
    for (int pf = 0; pf < 4; ++pf) {
      const int row = wp * 64 + pf * 16 + l15;
      s16x4 h0 = *(const s16x4*)&lds[bk][0][row][coff];
      s16x4 h1 = *(const s16x4*)&lds[bk][0][row][coff + 4];
      s16x4 l0 = *(const s16x4*)&lds[bk][1][row][coff];
      s16x4 l1 = *(const s16x4*)&lds[bk][1][row][coff + 4];
      Ah[pf] = __builtin_shufflevector(h0, h1, 0, 1, 2, 3, 4, 5, 6, 7);
      Al[pf] = __builtin_shufflevector(l0, l1, 0, 1, 2, 3, 4, 5, 6, 7);
    }

    const short* wh = whiF + ((size_t)(k * 16 + wo * 8) * 64 + lane) * 8;
    const short* wl = wloF + ((size_t)(k * 16 + wo * 8) * 64 + lane) * 8;
    s16x8 Bh = *(const s16x8*)wh;
    s16x8 Bl = *(const s16x8*)wl;
#pragma unroll
    for (int of = 0; of < 8; ++of) {
      s16x8 nBh = Bh, nBl = Bl;
      if (of < 7) {
        nBh = *(const s16x8*)(wh + (size_t)(of + 1) * 512);
        nBl = *(const s16x8*)(wl + (size_t)(of + 1) * 512);
      }
#pragma unroll
      for (int pf = 0; pf < 4; ++pf) {
        acc[pf][of] = __builtin_amdgcn_mfma_f32_16x16x32_bf16(Ah[pf], Bh, acc[pf][of], 0, 0, 0);
        acc[pf][of] = __builtin_amdgcn_mfma_f32_16x16x32_bf16(Ah[pf], Bl, acc[pf][of], 0, 0, 0);
        acc[pf][of] = __builtin_amdgcn_mfma_f32_16x16x32_bf16(Al[pf], Bh, acc[pf][of], 0, 0, 0);
      }
      Bh = nBh; Bl = nBl;
    }
  }

  float* fb = f1 + ((size_t)b << 22) + hw0;
  const int prow = wp * 64 + (lg << 2);
#pragma unroll
  for (int of = 0; of < 8; ++of) {
    const int o = wo * 128 + of * 16 + l15;
    float* fo = fb + ((size_t)o << 14);
#pragma unroll
    for (int pf = 0; pf < 4; ++pf)
      *(f32x4*)(fo + prow + pf * 16) = acc[pf][of];
  }
}

// ---------------------------------------------------------------------------
// Kernel 2: partial L1 distances (UNCHANGED this round -- control vs k_agg2's
// new stencil mechanism; port if R7 verifies).
// ---------------------------------------------------------------------------
__global__ __launch_bounds__(256) void k_dist(const float* __restrict__ f1,
                                              float* __restrict__ dist_part)
{
  const int t    = threadIdx.x;
  const int r    = t >> 5, cq = t & 31;
  const int lane = t & 63;
  const int h0 = blockIdx.x * 8;
  const int b  = blockIdx.y;
  const int c0 = blockIdx.z * 32;
  const int h  = h0 + r;
  const int hu = h == 0 ? 0 : h - 1;
  const int hd = h == 127 ? 127 : h + 1;
  const int colo = cq * 4;
  const float* plane0 = f1 + ((size_t)(b * 256 + c0)) * 16384;

  float acc[4][8];
#pragma unroll
  for (int i = 0; i < 4; ++i)
#pragma unroll
    for (int k = 0; k < 8; ++k) acc[i][k] = 0.f;

#pragma unroll 4
  for (int cc = 0; cc < 32; ++cc) {
    const float* pl = plane0 + (size_t)cc * 16384;
    float4 vv[3];
    vv[0] = *(const float4*)(pl + hu * 128 + colo);
    vv[1] = *(const float4*)(pl + h  * 128 + colo);
    vv[2] = *(const float4*)(pl + hd * 128 + colo);
    float vals[3][6];
#pragma unroll
    for (int d = 0; d < 3; ++d) {
      const float lf = __shfl(vv[d].w, (lane + 63) & 63, 64);
      const float rg = __shfl(vv[d].x, (lane + 1) & 63, 64);
      vals[d][0] = (cq == 0)  ? vv[d].x : lf;
      vals[d][1] = vv[d].x; vals[d][2] = vv[d].y;
      vals[d][3] = vv[d].z; vals[d][4] = vv[d].w;
      vals[d][5] = (cq == 31) ? vv[d].w : rg;
    }
#pragma unroll
    for (int i = 0; i < 4; ++i) {
      const float cv = vals[1][i + 1];
      acc[i][0] += fabsf(cv - vals[0][i]);
      acc[i][1] += fabsf(cv - vals[0][i + 1]);
      acc[i][2] += fabsf(cv - vals[0][i + 2]);
      acc[i][3] += fabsf(cv - vals[1][i]);
      acc[i][4] += fabsf(cv - vals[1][i + 2]);
      acc[i][5] += fabsf(cv - vals[2][i]);
      acc[i][6] += fabsf(cv - vals[2][i + 1]);
      acc[i][7] += fabsf(cv - vals[2][i + 2]);
    }
  }

  const int p = (b << 14) + h * 128 + colo;
  float* base = dist_part + ((size_t)blockIdx.z << 19);   // chunk * 8*65536
#pragma unroll
  for (int k = 0; k < 8; ++k) {
    float4 v; v.x = acc[0][k]; v.y = acc[1][k]; v.z = acc[2][k]; v.w = acc[3][k];
    *(float4*)(base + (size_t)k * 65536 + p) = v;
  }
}

// ---------------------------------------------------------------------------
// Kernel 2b: sum the 8 chunk-partials per pixel, softmax once, write wts[p][8].
// ---------------------------------------------------------------------------
__global__ __launch_bounds__(256) void k_soft(const float* __restrict__ dist_part,
                                              const float* __restrict__ rp,
                                              float* __restrict__ wts)
{
  const int p = blockIdx.x * 256 + threadIdx.x;
  const float rv = rp[0];
  float d[8];
#pragma unroll
  for (int k = 0; k < 8; ++k) d[k] = 0.f;
  for (int ch = 0; ch < 8; ++ch) {
    const float* base = dist_part + ((size_t)ch << 19);
#pragma unroll
    for (int k = 0; k < 8; ++k) d[k] += base[(size_t)k * 65536 + p];
  }
  float lg[8];
  float mx = -rv * d[0];
#pragma unroll
  for (int k = 1; k < 8; ++k) mx = fmaxf(mx, -rv * d[k]);
  float sm = 0.f;
#pragma unroll
  for (int k = 0; k < 8; ++k) { lg[k] = __expf(fmaf(-rv, d[k], -mx)); sm += lg[k]; }
  const float inv = 1.f / sm;
  float4 w0, w1;
  w0.x = lg[0] * inv; w0.y = lg[1] * inv; w0.z = lg[2] * inv; w0.w = lg[3] * inv;
  w1.x = lg[4] * inv; w1.y = lg[5] * inv; w1.z = lg[6] * inv; w1.w = lg[7] * inv;
  *(float4*)(wts + (size_t)p * 8)     = w0;
  *(float4*)(wts + (size_t)p * 8 + 4) = w1;
}

// ---------------------------------------------------------------------------
// Kernel 3: weighted aggregation + residual + fused BN stats.
// R7 (post-mortem of R6's 200us regression; R5 was 116us):
//  * grid REVERTED to (16,4,8): 32ch/block restores wts amortization
//    (R6's 4x grid split stretched the kernel: fixed prologue/epilogue
//    per block stopped amortizing; VALU-cycles were constant).
//  * stencil shuffles -> clamped scalar L1 loads: vals[d][0]/[5] are
//    pl[row+colo-1]/pl[row+colo+4] (row-edge clamped). Removes 6 serial
//    DS ops + 2 cndmask per iteration from the critical path.
//  * butterfly deferred in GROUPS of 8 channels: 16 independent 6-deep
//    shuffle chains per group (4x ILP) instead of a 12-op serial chain
//    per iteration; one lane-0 atomic batch per group.
// ---------------------------------------------------------------------------
__global__ __launch_bounds__(256, 2) void k_agg2(const float* __restrict__ f1,
                                                 const float* __restrict__ x,
                                                 const float* __restrict__ wts,
                                                 float* __restrict__ bn_in,
                                                 float* __restrict__ s1,
                                                 float* __restrict__ s2)
{
  const int t    = threadIdx.x;
  const int r    = t >> 5, cq = t & 31;
  const int lane = t & 63;
  const int h0 = blockIdx.x * 8;
  const int b  = blockIdx.y;
  const int c0 = blockIdx.z * 32;
  const int h  = h0 + r;
  const int hu = h == 0 ? 0 : h - 1;
  const int hd = h == 127 ? 127 : h + 1;
  const int colo = cq * 4;
  const int lidx = (cq == 0)  ? 0   : colo - 1;   // left-neighbor col (clamped)
  const int ridx = (cq == 31) ? 127 : colo + 4;   // right-neighbor col (clamped)
  const int p  = (b << 14) + h * 128 + colo;

  float m[4][8];
#pragma unroll
  for (int i = 0; i < 4; ++i) {
    float4 w0 = *(const float4*)(wts + (size_t)(p + i) * 8);
    float4 w1 = *(const float4*)(wts + (size_t)(p + i) * 8 + 4);
    m[i][0] = w0.x; m[i][1] = w0.y; m[i][2] = w0.z; m[i][3] = w0.w;
    m[i][4] = w1.x; m[i][5] = w1.y; m[i][6] = w1.z; m[i][7] = w1.w;
  }

  const float* plane0 = f1 + ((size_t)(b * 256 + c0)) * 16384;

#pragma unroll
  for (int g = 0; g < 4; ++g) {
    float ss[8], qq[8];
#pragma unroll
    for (int c8 = 0; c8 < 8; ++c8) {
      const int cc = g * 8 + c8;
      const float* pl = plane0 + (size_t)cc * 16384;
      const float* pu = pl + hu * 128;
      const float* pm = pl + h  * 128;
      const float* pd = pl + hd * 128;
      // vector center loads + clamped scalar edge loads (L1-hit: same lines)
      float4 vu = *(const float4*)(pu + colo);
      float4 vm = *(const float4*)(pm + colo);
      float4 vd = *(const float4*)(pd + colo);
      float lu = pu[lidx], ru = pu[ridx];
      float lm = pm[lidx], rm = pm[ridx];
      float ld = pd[lidx], rd = pd[ridx];

      float vals[3][6];
      vals[0][0] = lu; vals[0][1] = vu.x; vals[0][2] = vu.y;
      vals[0][3] = vu.z; vals[0][4] = vu.w; vals[0][5] = ru;
      vals[1][0] = lm; vals[1][1] = vm.x; vals[1][2] = vm.y;
      vals[1][3] = vm.z; vals[1][4] = vm.w; vals[1][5] = rm;
      vals[2][0] = ld; vals[2][1] = vd.x; vals[2][2] = vd.y;
      vals[2][3] = vd.z; vals[2][4] = vd.w; vals[2][5] = rd;

      const size_t chanoff = ((size_t)(b * 256 + c0 + cc)) * 16384 +
                             (size_t)h * 128 + colo;
      const float4 xv = *(const float4*)(x + chanoff);
      float o_[4] = {xv.x, xv.y, xv.z, xv.w};
#pragma unroll
      for (int i = 0; i < 4; ++i) {
        o_[i] = fmaf(m[i][0], vals[0][i],     o_[i]);
        o_[i] = fmaf(m[i][1], vals[0][i + 1], o_[i]);
        o_[i] = fmaf(m[i][2], vals[0][i + 2], o_[i]);
        o_[i] = fmaf(m[i][3], vals[1][i],     o_[i]);
        o_[i] = fmaf(m[i][4], vals[1][i + 2], o_[i]);
        o_[i] = fmaf(m[i][5], vals[2][i],     o_[i]);
        o_[i] = fmaf(m[i][6], vals[2][i + 1], o_[i]);
        o_[i] = fmaf(m[i][7], vals[2][i + 2], o_[i]);
      }
      float4 ov; ov.x = o_[0]; ov.y = o_[1]; ov.z = o_[2]; ov.w = o_[3];
      *(float4*)(bn_in + chanoff) = ov;

      ss[c8] = o_[0] + o_[1] + o_[2] + o_[3];
      qq[c8] = o_[0] * o_[0] + o_[1] * o_[1] + o_[2] * o_[2] + o_[3] * o_[3];
    }
    // 16 independent butterfly chains for this channel group
#pragma unroll
    for (int c8 = 0; c8 < 8; ++c8) {
#pragma unroll
      for (int msk = 1; msk < 64; msk <<= 1) {
        ss[c8] += __shfl_xor(ss[c8], msk, 64);
        qq[c8] += __shfl_xor(qq[c8], msk, 64);
      }
    }
    if (lane == 0) {
#pragma unroll
      for (int c8 = 0; c8 < 8; ++c8) {
        atomicAdd(&s1[c0 + g * 8 + c8], ss[c8]);
        atomicAdd(&s2[c0 + g * 8 + c8], qq[c8]);
      }
    }
  }
}

// ---------------------------------------------------------------------------
// Kernel 4: BN folds
// ---------------------------------------------------------------------------
__global__ void k_stats(const float* __restrict__ s1, const float* __restrict__ s2,
                        const float* __restrict__ gamma, const float* __restrict__ beta,
                        float* __restrict__ scale, float* __restrict__ shift)
{
  const int c = threadIdx.x;
  const float n = 65536.f;
  const float mean = s1[c] / n;
  const float var  = s2[c] / n - mean * mean;
  const float sc   = gamma[c] * rsqrtf(var + EPS_);
  scale[c] = sc;
  shift[c] = beta[c] - mean * sc;
}

// ---------------------------------------------------------------------------
// Kernel 5: elementwise BN affine + LeakyReLU
// ---------------------------------------------------------------------------
__global__ __launch_bounds__(256) void k_apply(const float* __restrict__ bn_in,
                                               const float* __restrict__ scale,
                                               const float* __restrict__ shift,
                                               float* __restrict__ out)
{
  const int base = blockIdx.x * 1024 + threadIdx.x;   // float4 index
#pragma unroll
  for (int j = 0; j < 4; ++j) {
    const int idx = base + j * 256;
    const int c   = (idx >> 12) & 255;
    const float sc = scale[c], sh = shift[c];
    const float4 v = *(const float4*)(bn_in + (size_t)idx * 4);
    float4 o;
    float u;
    u = fmaf(v.x, sc, sh); o.x = u > 0.f ? u : 0.01f * u;
    u = fmaf(v.y, sc, sh); o.y = u > 0.f ? u : 0.01f * u;
    u = fmaf(v.z, sc, sh); o.z = u > 0.f ? u : 0.01f * u;
    u = fmaf(v.w, sc, sh); o.w = u > 0.f ? u : 0.01f * u;
    *(float4*)(out + (size_t)idx * 4) = o;
  }
}

// ---------------------------------------------------------------------------
// Workspace: f1 64MB | bn_in 64MB (dist_part 16MB aliases its head; wfrag
// 256KB parks at bn_in+32MB -- both dead before k_agg2 writes) | wts 2MB |
// s1/s2/scale/shift 4KB.  Total ~130MB (unchanged).
// ---------------------------------------------------------------------------
extern "C" void kernel_launch(void* const* d_in, const int* in_sizes, int n_in,
                              void* d_out, int out_size, void* d_ws, size_t ws_size,
                              hipStream_t stream)
{
  const float* x     = (const float*)d_in[0];
  const float* W1    = (const float*)d_in[1];
  const float* b1    = (const float*)d_in[2];
  const float* r     = (const float*)d_in[3];
  const float* gamma = (const float*)d_in[4];
  const float* beta  = (const float*)d_in[5];
  float* out = (float*)d_out;

  char* ws = (char*)d_ws;
  float* f1        = (float*)ws;                           // 64 MB
  float* bn_in     = (float*)(ws + ((size_t)64 << 20));    // 64 MB
  float* dist_part = bn_in;                                // 16 MB alias (dead before bn_in written)
  short* whiF      = (short*)(ws + ((size_t)96 << 20));    // 128 KB (inside bn_in, dead region)
  short* wloF      = whiF + 65536;                         // 128 KB
  float* wts       = (float*)(ws + ((size_t)128 << 20));   // 2 MB
  float* s1        = wts + 524288;
  float* s2        = s1 + 256;
  float* scale     = s1 + 512;
  float* shift     = s1 + 768;

  hipMemsetAsync(s1, 0, 512 * sizeof(float), stream);

  k_wprep<<<dim3(32),        256, 0, stream>>>(W1, whiF, wloF);
  k_mm   <<<dim3(128, 4),    256, 0, stream>>>(x, whiF, wloF, b1, f1);
  k_dist <<<dim3(16, 4, 8),  256, 0, stream>>>(f1, dist_part);
  k_soft <<<dim3(256),       256, 0, stream>>>(dist_part, r, wts);
  k_agg2 <<<dim3(16, 4, 8),  256, 0, stream>>>(f1, x, wts, bn_in, s1, s2);
  k_stats<<<dim3(1),         256, 0, stream>>>(s1, s2, gamma, beta, scale, shift);
  k_apply<<<dim3(4096),      256, 0, stream>>>(bn_in, scale, shift, out);
}

// Round 9
// 311.828 us; speedup vs baseline: 1.2784x; 1.1080x over previous
//
#include <hip/hip_runtime.h>
#include <cstddef>

// Problem: B=4, C=256, H=W=128, HW=16384, NPIX=65536
#define EPS_ 1e-5f

typedef __attribute__((ext_vector_type(8))) short s16x8;
typedef __attribute__((ext_vector_type(4))) short s16x4;
typedef __attribute__((ext_vector_type(4))) float f32x4;

__device__ __forceinline__ unsigned short f2bf(float f) {
  unsigned u = __builtin_bit_cast(unsigned, f);
  return (unsigned short)((u + 0x7fffu + ((u >> 16) & 1u)) >> 16);   // RNE
}
__device__ __forceinline__ float bf2f(unsigned short h) {
  return __builtin_bit_cast(float, ((unsigned)h) << 16);
}

// ---------------------------------------------------------------------------
// Kernel 0: pre-convert W1 into MFMA B-fragment layout, hi/lo bf16 split.
// ---------------------------------------------------------------------------
__global__ __launch_bounds__(256) void k_wprep(const float* __restrict__ W1,
                                               short* __restrict__ whiF,
                                               short* __restrict__ wloF)
{
  const int tid = blockIdx.x * 256 + threadIdx.x;   // 0..8191
  const int k  = tid >> 10;
  const int n  = (tid >> 6) & 15;
  const int l  = tid & 63;
  const int o  = n * 16 + (l & 15);
  const int cb = k * 32 + ((l >> 4) << 3);
  const float* src = W1 + o * 256 + cb;
  s16x8 hv, lv;
#pragma unroll
  for (int j = 0; j < 8; ++j) {
    const float v = src[j];
    const unsigned short hb = f2bf(v);
    hv[j] = (short)hb;
    lv[j] = (short)f2bf(v - bf2f(hb));
  }
  *(s16x8*)(whiF + (size_t)tid * 8) = hv;
  *(s16x8*)(wloF + (size_t)tid * 8) = lv;
}

// ---------------------------------------------------------------------------
// Kernel 1: GEMM via bf16 MFMA with 2-term split (3 mfma per K-chunk pair).
// (Verified R5: total -65.7us vs fp32 VALU GEMM, absmax 0.0156 passed.)
// ---------------------------------------------------------------------------
#define RS 36
__global__ __launch_bounds__(256, 2) void k_mm(const float* __restrict__ x,
                                               const short* __restrict__ whiF,
                                               const short* __restrict__ wloF,
                                               const float* __restrict__ b1,
                                               float* __restrict__ f1)
{
  __shared__ short lds[2][2][128][RS];   // [dbuf][hi/lo][p][c]  36864 B
  const int tid  = threadIdx.x;
  const int lane = tid & 63;
  const int wid  = tid >> 6;
  const int wp   = wid & 1;
  const int wo   = wid >> 1;
  const int l15  = lane & 15, lg = lane >> 4;
  const int hw0  = blockIdx.x * 128;
  const int b    = blockIdx.y;
  const float* xb = x + ((size_t)b << 22) + hw0;

  const int ps = tid & 127;
  const int cg = tid >> 7;

  f32x4 acc[4][8];
#pragma unroll
  for (int of = 0; of < 8; ++of) {
    const float bias = b1[wo * 128 + of * 16 + l15];
#pragma unroll
    for (int pf = 0; pf < 4; ++pf) {
      acc[pf][of][0] = bias; acc[pf][of][1] = bias;
      acc[pf][of][2] = bias; acc[pf][of][3] = bias;
    }
  }

  float xr[16];
#pragma unroll
  for (int j = 0; j < 16; ++j)
    xr[j] = xb[(size_t)(cg * 16 + j) * 16384 + ps];

  for (int k = 0; k < 8; ++k) {
    const int bk = k & 1;
#pragma unroll
    for (int a = 0; a < 4; ++a) {
      s16x4 hv, lv;
#pragma unroll
      for (int j = 0; j < 4; ++j) {
        const float v = xr[a * 4 + j];
        const unsigned short hb = f2bf(v);
        hv[j] = (short)hb;
        lv[j] = (short)f2bf(v - bf2f(hb));
      }
      *(s16x4*)&lds[bk][0][ps][cg * 16 + a * 4] = hv;
      *(s16x4*)&lds[bk][1][ps][cg * 16 + a * 4] = lv;
    }
    __syncthreads();

    if (k < 7) {
#pragma unroll
      for (int j = 0; j < 16; ++j)
        xr[j] = xb[(size_t)((k + 1) * 32 + cg * 16 + j) * 16384 + ps];
    }

    s16x8 Ah[4], Al[4];
    const int coff = lg << 3;
#pragma unroll
    for (int pf = 0; pf < 4; ++pf) {
      const int row = wp * 64 + pf * 16 + l15;
      s16x4 h0 = *(const s16x4*)&lds[bk][0][row][coff];
      s16x4 h1 = *(const s16x4*)&lds[bk][0][row][coff + 4];
      s16x4 l0 = *(const s16x4*)&lds[bk][1][row][coff];
      s16x4 l1 = *(const s16x4*)&lds[bk][1][row][coff + 4];
      Ah[pf] = __builtin_shufflevector(h0, h1, 0, 1, 2, 3, 4, 5, 6, 7);
      Al[pf] = __builtin_shufflevector(l0, l1, 0, 1, 2, 3, 4, 5, 6, 7);
    }

    const short* wh = whiF + ((size_t)(k * 16 + wo * 8) * 64 + lane) * 8;
    const short* wl = wloF + ((size_t)(k * 16 + wo * 8) * 64 + lane) * 8;
    s16x8 Bh = *(const s16x8*)wh;
    s16x8 Bl = *(const s16x8*)wl;
#pragma unroll
    for (int of = 0; of < 8; ++of) {
      s16x8 nBh = Bh, nBl = Bl;
      if (of < 7) {
        nBh = *(const s16x8*)(wh + (size_t)(of + 1) * 512);
        nBl = *(const s16x8*)(wl + (size_t)(of + 1) * 512);
      }
#pragma unroll
      for (int pf = 0; pf < 4; ++pf) {
        acc[pf][of] = __builtin_amdgcn_mfma_f32_16x16x32_bf16(Ah[pf], Bh, acc[pf][of], 0, 0, 0);
        acc[pf][of] = __builtin_amdgcn_mfma_f32_16x16x32_bf16(Ah[pf], Bl, acc[pf][of], 0, 0, 0);
        acc[pf][of] = __builtin_amdgcn_mfma_f32_16x16x32_bf16(Al[pf], Bh, acc[pf][of], 0, 0, 0);
      }
      Bh = nBh; Bl = nBl;
    }
  }

  float* fb = f1 + ((size_t)b << 22) + hw0;
  const int prow = wp * 64 + (lg << 2);
#pragma unroll
  for (int of = 0; of < 8; ++of) {
    const int o = wo * 128 + of * 16 + l15;
    float* fo = fb + ((size_t)o << 14);
#pragma unroll
    for (int pf = 0; pf < 4; ++pf)
      *(f32x4*)(fo + prow + pf * 16) = acc[pf][of];
  }
}

// ---------------------------------------------------------------------------
// Kernel 2: partial L1 distances (UNCHANGED -- control; port LDS staging if
// R8's k_agg2 mechanism verifies).
// ---------------------------------------------------------------------------
__global__ __launch_bounds__(256) void k_dist(const float* __restrict__ f1,
                                              float* __restrict__ dist_part)
{
  const int t    = threadIdx.x;
  const int r    = t >> 5, cq = t & 31;
  const int lane = t & 63;
  const int h0 = blockIdx.x * 8;
  const int b  = blockIdx.y;
  const int c0 = blockIdx.z * 32;
  const int h  = h0 + r;
  const int hu = h == 0 ? 0 : h - 1;
  const int hd = h == 127 ? 127 : h + 1;
  const int colo = cq * 4;
  const float* plane0 = f1 + ((size_t)(b * 256 + c0)) * 16384;

  float acc[4][8];
#pragma unroll
  for (int i = 0; i < 4; ++i)
#pragma unroll
    for (int k = 0; k < 8; ++k) acc[i][k] = 0.f;

#pragma unroll 4
  for (int cc = 0; cc < 32; ++cc) {
    const float* pl = plane0 + (size_t)cc * 16384;
    float4 vv[3];
    vv[0] = *(const float4*)(pl + hu * 128 + colo);
    vv[1] = *(const float4*)(pl + h  * 128 + colo);
    vv[2] = *(const float4*)(pl + hd * 128 + colo);
    float vals[3][6];
#pragma unroll
    for (int d = 0; d < 3; ++d) {
      const float lf = __shfl(vv[d].w, (lane + 63) & 63, 64);
      const float rg = __shfl(vv[d].x, (lane + 1) & 63, 64);
      vals[d][0] = (cq == 0)  ? vv[d].x : lf;
      vals[d][1] = vv[d].x; vals[d][2] = vv[d].y;
      vals[d][3] = vv[d].z; vals[d][4] = vv[d].w;
      vals[d][5] = (cq == 31) ? vv[d].w : rg;
    }
#pragma unroll
    for (int i = 0; i < 4; ++i) {
      const float cv = vals[1][i + 1];
      acc[i][0] += fabsf(cv - vals[0][i]);
      acc[i][1] += fabsf(cv - vals[0][i + 1]);
      acc[i][2] += fabsf(cv - vals[0][i + 2]);
      acc[i][3] += fabsf(cv - vals[1][i]);
      acc[i][4] += fabsf(cv - vals[1][i + 2]);
      acc[i][5] += fabsf(cv - vals[2][i]);
      acc[i][6] += fabsf(cv - vals[2][i + 1]);
      acc[i][7] += fabsf(cv - vals[2][i + 2]);
    }
  }

  const int p = (b << 14) + h * 128 + colo;
  float* base = dist_part + ((size_t)blockIdx.z << 19);   // chunk * 8*65536
#pragma unroll
  for (int k = 0; k < 8; ++k) {
    float4 v; v.x = acc[0][k]; v.y = acc[1][k]; v.z = acc[2][k]; v.w = acc[3][k];
    *(float4*)(base + (size_t)k * 65536 + p) = v;
  }
}

// ---------------------------------------------------------------------------
// Kernel 2b: sum the 8 chunk-partials per pixel, softmax once, write wts[p][8].
// ---------------------------------------------------------------------------
__global__ __launch_bounds__(256) void k_soft(const float* __restrict__ dist_part,
                                              const float* __restrict__ rp,
                                              float* __restrict__ wts)
{
  const int p = blockIdx.x * 256 + threadIdx.x;
  const float rv = rp[0];
  float d[8];
#pragma unroll
  for (int k = 0; k < 8; ++k) d[k] = 0.f;
  for (int ch = 0; ch < 8; ++ch) {
    const float* base = dist_part + ((size_t)ch << 19);
#pragma unroll
    for (int k = 0; k < 8; ++k) d[k] += base[(size_t)k * 65536 + p];
  }
  float lg[8];
  float mx = -rv * d[0];
#pragma unroll
  for (int k = 1; k < 8; ++k) mx = fmaxf(mx, -rv * d[k]);
  float sm = 0.f;
#pragma unroll
  for (int k = 0; k < 8; ++k) { lg[k] = __expf(fmaf(-rv, d[k], -mx)); sm += lg[k]; }
  const float inv = 1.f / sm;
  float4 w0, w1;
  w0.x = lg[0] * inv; w0.y = lg[1] * inv; w0.z = lg[2] * inv; w0.w = lg[3] * inv;
  w1.x = lg[4] * inv; w1.y = lg[5] * inv; w1.z = lg[6] * inv; w1.w = lg[7] * inv;
  *(float4*)(wts + (size_t)p * 8)     = w0;
  *(float4*)(wts + (size_t)p * 8 + 4) = w1;
}

// ---------------------------------------------------------------------------
// Kernel 3: weighted aggregation + residual + fused BN stats.
// R8 resubmit (R8 never ran -- broker timeout). Post-mortems: R6 grid-split
// 200us FAIL, R7 edge-scalar-loads 147us FAIL; R5 best 116us. Shared symptom:
// ~4300 cyc/channel-iter, VALUxdur constant -> stall is per-iteration
// GLOBAL-load latency, unpipelined at VGPR=52. Mechanism change:
//  * f1 tile (10 rows x 128 cols) LDS-STAGED per channel, double-buffered;
//    staging loads for cc+1 issued BEFORE computing cc (T14 issue-early).
//    Global VMEM/thread/iter: 4 -> 2.25; stencil served by ds_read (~120cy).
//  * edge neighbors read directly from LDS (no shuffles, no global edges).
//  * grid/butterfly/atomics: R5 structure (16,4,8), per-channel butterfly.
// ---------------------------------------------------------------------------
__global__ __launch_bounds__(256, 2) void k_agg2(const float* __restrict__ f1,
                                                 const float* __restrict__ x,
                                                 const float* __restrict__ wts,
                                                 float* __restrict__ bn_in,
                                                 float* __restrict__ s1,
                                                 float* __restrict__ s2)
{
  __shared__ float tile[2][10][128];     // [dbuf][row][col] 10 KB
  const int t    = threadIdx.x;
  const int r    = t >> 5, cq = t & 31;
  const int lane = t & 63;
  const int h0 = blockIdx.x * 8;
  const int b  = blockIdx.y;
  const int c0 = blockIdx.z * 32;
  const int h  = h0 + r;
  const int colo = cq * 4;
  const int lidx = (cq == 0)  ? 0   : colo - 1;   // clamped left col
  const int ridx = (cq == 31) ? 127 : colo + 4;   // clamped right col
  const int p  = (b << 14) + h * 128 + colo;

  // staging map: float4 idx in [0,320): row=idx>>5 (0..9), col4=idx&31
  const int si0 = t;                   // all threads
  const int si1 = 256 + t;             // threads 0..63 only
  const int sr0 = si0 >> 5, sc0_ = si0 & 31;
  const int sr1 = si1 >> 5, sc1_ = si1 & 31;
  const int gr0 = min(max(h0 - 1 + sr0, 0), 127);
  const int gr1 = min(max(h0 - 1 + sr1, 0), 127);

  float m[4][8];
#pragma unroll
  for (int i = 0; i < 4; ++i) {
    float4 w0 = *(const float4*)(wts + (size_t)(p + i) * 8);
    float4 w1 = *(const float4*)(wts + (size_t)(p + i) * 8 + 4);
    m[i][0] = w0.x; m[i][1] = w0.y; m[i][2] = w0.z; m[i][3] = w0.w;
    m[i][4] = w1.x; m[i][5] = w1.y; m[i][6] = w1.z; m[i][7] = w1.w;
  }

  const float* plane0 = f1 + ((size_t)(b * 256 + c0)) * 16384;

  // prologue: stage channel 0 into buf 0
  {
    const float* pl = plane0;
    float4 a0 = *(const float4*)(pl + gr0 * 128 + sc0_ * 4);
    *(float4*)&tile[0][sr0][sc0_ * 4] = a0;
    if (t < 64) {
      float4 a1 = *(const float4*)(pl + gr1 * 128 + sc1_ * 4);
      *(float4*)&tile[0][sr1][sc1_ * 4] = a1;
    }
  }
  __syncthreads();

  for (int cc = 0; cc < 32; ++cc) {
    const int cur = cc & 1, nxt = cur ^ 1;

    // ---- issue staging loads for cc+1 EARLY (hide under compute) ----
    float4 a0n, a1n;
    if (cc < 31) {
      const float* pln = plane0 + (size_t)(cc + 1) * 16384;
      a0n = *(const float4*)(pln + gr0 * 128 + sc0_ * 4);
      if (t < 64) a1n = *(const float4*)(pln + gr1 * 128 + sc1_ * 4);
    }

    // ---- stencil from LDS: center row r+1, up r, down r+2 ----
    float vals[3][6];
#pragma unroll
    for (int d = 0; d < 3; ++d) {
      const float* row = &tile[cur][r + d][0];
      float4 c4 = *(const float4*)(row + colo);
      vals[d][0] = row[lidx];
      vals[d][1] = c4.x; vals[d][2] = c4.y;
      vals[d][3] = c4.z; vals[d][4] = c4.w;
      vals[d][5] = row[ridx];
    }

    const size_t chanoff = ((size_t)(b * 256 + c0 + cc)) * 16384 +
                           (size_t)h * 128 + colo;
    const float4 xv = *(const float4*)(x + chanoff);
    float o_[4] = {xv.x, xv.y, xv.z, xv.w};
#pragma unroll
    for (int i = 0; i < 4; ++i) {
      o_[i] = fmaf(m[i][0], vals[0][i],     o_[i]);
      o_[i] = fmaf(m[i][1], vals[0][i + 1], o_[i]);
      o_[i] = fmaf(m[i][2], vals[0][i + 2], o_[i]);
      o_[i] = fmaf(m[i][3], vals[1][i],     o_[i]);
      o_[i] = fmaf(m[i][4], vals[1][i + 2], o_[i]);
      o_[i] = fmaf(m[i][5], vals[2][i],     o_[i]);
      o_[i] = fmaf(m[i][6], vals[2][i + 1], o_[i]);
      o_[i] = fmaf(m[i][7], vals[2][i + 2], o_[i]);
    }
    float4 ov; ov.x = o_[0]; ov.y = o_[1]; ov.z = o_[2]; ov.w = o_[3];
    *(float4*)(bn_in + chanoff) = ov;

    float s = o_[0] + o_[1] + o_[2] + o_[3];
    float q = o_[0] * o_[0] + o_[1] * o_[1] + o_[2] * o_[2] + o_[3] * o_[3];
#pragma unroll
    for (int msk = 1; msk < 64; msk <<= 1) {
      s += __shfl_xor(s, msk, 64);
      q += __shfl_xor(q, msk, 64);
    }
    if (lane == 0) {
      atomicAdd(&s1[c0 + cc], s);
      atomicAdd(&s2[c0 + cc], q);
    }

    // ---- write staged regs, one barrier per channel ----
    if (cc < 31) {
      *(float4*)&tile[nxt][sr0][sc0_ * 4] = a0n;
      if (t < 64) *(float4*)&tile[nxt][sr1][sc1_ * 4] = a1n;
    }
    __syncthreads();
  }
}

// ---------------------------------------------------------------------------
// Kernel 4: BN folds
// ---------------------------------------------------------------------------
__global__ void k_stats(const float* __restrict__ s1, const float* __restrict__ s2,
                        const float* __restrict__ gamma, const float* __restrict__ beta,
                        float* __restrict__ scale, float* __restrict__ shift)
{
  const int c = threadIdx.x;
  const float n = 65536.f;
  const float mean = s1[c] / n;
  const float var  = s2[c] / n - mean * mean;
  const float sc   = gamma[c] * rsqrtf(var + EPS_);
  scale[c] = sc;
  shift[c] = beta[c] - mean * sc;
}

// ---------------------------------------------------------------------------
// Kernel 5: elementwise BN affine + LeakyReLU
// ---------------------------------------------------------------------------
__global__ __launch_bounds__(256) void k_apply(const float* __restrict__ bn_in,
                                               const float* __restrict__ scale,
                                               const float* __restrict__ shift,
                                               float* __restrict__ out)
{
  const int base = blockIdx.x * 1024 + threadIdx.x;   // float4 index
#pragma unroll
  for (int j = 0; j < 4; ++j) {
    const int idx = base + j * 256;
    const int c   = (idx >> 12) & 255;
    const float sc = scale[c], sh = shift[c];
    const float4 v = *(const float4*)(bn_in + (size_t)idx * 4);
    float4 o;
    float u;
    u = fmaf(v.x, sc, sh); o.x = u > 0.f ? u : 0.01f * u;
    u = fmaf(v.y, sc, sh); o.y = u > 0.f ? u : 0.01f * u;
    u = fmaf(v.z, sc, sh); o.z = u > 0.f ? u : 0.01f * u;
    u = fmaf(v.w, sc, sh); o.w = u > 0.f ? u : 0.01f * u;
    *(float4*)(out + (size_t)idx * 4) = o;
  }
}

// ---------------------------------------------------------------------------
// Workspace: f1 64MB | bn_in 64MB (dist_part 16MB aliases its head; wfrag
// 256KB parks at bn_in+32MB -- both dead before k_agg2 writes) | wts 2MB |
// s1/s2/scale/shift 4KB.  Total ~130MB (unchanged).
// ---------------------------------------------------------------------------
extern "C" void kernel_launch(void* const* d_in, const int* in_sizes, int n_in,
                              void* d_out, int out_size, void* d_ws, size_t ws_size,
                              hipStream_t stream)
{
  const float* x     = (const float*)d_in[0];
  const float* W1    = (const float*)d_in[1];
  const float* b1    = (const float*)d_in[2];
  const float* r     = (const float*)d_in[3];
  const float* gamma = (const float*)d_in[4];
  const float* beta  = (const float*)d_in[5];
  float* out = (float*)d_out;

  char* ws = (char*)d_ws;
  float* f1        = (float*)ws;                           // 64 MB
  float* bn_in     = (float*)(ws + ((size_t)64 << 20));    // 64 MB
  float* dist_part = bn_in;                                // 16 MB alias (dead before bn_in written)
  short* whiF      = (short*)(ws + ((size_t)96 << 20));    // 128 KB (inside bn_in, dead region)
  short* wloF      = whiF + 65536;                         // 128 KB
  float* wts       = (float*)(ws + ((size_t)128 << 20));   // 2 MB
  float* s1        = wts + 524288;
  float* s2        = s1 + 256;
  float* scale     = s1 + 512;
  float* shift     = s1 + 768;

  hipMemsetAsync(s1, 0, 512 * sizeof(float), stream);

  k_wprep<<<dim3(32),        256, 0, stream>>>(W1, whiF, wloF);
  k_mm   <<<dim3(128, 4),    256, 0, stream>>>(x, whiF, wloF, b1, f1);
  k_dist <<<dim3(16, 4, 8),  256, 0, stream>>>(f1, dist_part);
  k_soft <<<dim3(256),       256, 0, stream>>>(dist_part, r, wts);
  k_agg2 <<<dim3(16, 4, 8),  256, 0, stream>>>(f1, x, wts, bn_in, s1, s2);
  k_stats<<<dim3(1),         256, 0, stream>>>(s1, s2, gamma, beta, scale, shift);
  k_apply<<<dim3(4096),      256, 0, stream>>>(bn_in, scale, shift, out);
}

// Round 10
// 241.303 us; speedup vs baseline: 1.6520x; 1.2923x over previous
//
#include <hip/hip_runtime.h>
#include <cstddef>

// Problem: B=4, C=256, H=W=128, HW=16384, NPIX=65536
#define EPS_ 1e-5f

typedef __attribute__((ext_vector_type(8))) short s16x8;
typedef __attribute__((ext_vector_type(4))) short s16x4;
typedef __attribute__((ext_vector_type(4))) float f32x4;

__device__ __forceinline__ unsigned short f2bf(float f) {
  unsigned u = __builtin_bit_cast(unsigned, f);
  return (unsigned short)((u + 0x7fffu + ((u >> 16) & 1u)) >> 16);   // RNE
}
__device__ __forceinline__ float bf2f(unsigned short h) {
  return __builtin_bit_cast(float, ((unsigned)h) << 16);
}

// ---------------------------------------------------------------------------
// Kernel 0: pre-convert W1 into MFMA B-fragment layout, hi/lo bf16 split.
// ---------------------------------------------------------------------------
__global__ __launch_bounds__(256) void k_wprep(const float* __restrict__ W1,
                                               short* __restrict__ whiF,
                                               short* __restrict__ wloF)
{
  const int tid = blockIdx.x * 256 + threadIdx.x;   // 0..8191
  const int k  = tid >> 10;
  const int n  = (tid >> 6) & 15;
  const int l  = tid & 63;
  const int o  = n * 16 + (l & 15);
  const int cb = k * 32 + ((l >> 4) << 3);
  const float* src = W1 + o * 256 + cb;
  s16x8 hv, lv;
#pragma unroll
  for (int j = 0; j < 8; ++j) {
    const float v = src[j];
    const unsigned short hb = f2bf(v);
    hv[j] = (short)hb;
    lv[j] = (short)f2bf(v - bf2f(hb));
  }
  *(s16x8*)(whiF + (size_t)tid * 8) = hv;
  *(s16x8*)(wloF + (size_t)tid * 8) = lv;
}

// ---------------------------------------------------------------------------
// Kernel 1: GEMM via bf16 MFMA with 2-term split (3 mfma per K-chunk pair).
// (Verified R5: total -65.7us vs fp32 VALU GEMM, absmax 0.0156 passed.)
// ---------------------------------------------------------------------------
#define RS 36
__global__ __launch_bounds__(256, 2) void k_mm(const float* __restrict__ x,
                                               const short* __restrict__ whiF,
                                               const short* __restrict__ wloF,
                                               const float* __restrict__ b1,
                                               float* __restrict__ f1)
{
  __shared__ short lds[2][2][128][RS];   // [dbuf][hi/lo][p][c]  36864 B
  const int tid  = threadIdx.x;
  const int lane = tid & 63;
  const int wid  = tid >> 6;
  const int wp   = wid & 1;
  const int wo   = wid >> 1;
  const int l15  = lane & 15, lg = lane >> 4;
  const int hw0  = blockIdx.x * 128;
  const int b    = blockIdx.y;
  const float* xb = x + ((size_t)b << 22) + hw0;

  const int ps = tid & 127;
  const int cg = tid >> 7;

  f32x4 acc[4][8];
#pragma unroll
  for (int of = 0; of < 8; ++of) {
    const float bias = b1[wo * 128 + of * 16 + l15];
#pragma unroll
    for (int pf = 0; pf < 4; ++pf) {
      acc[pf][of][0] = bias; acc[pf][of][1] = bias;
      acc[pf][of][2] = bias; acc[pf][of][3] = bias;
    }
  }

  float xr[16];
#pragma unroll
  for (int j = 0; j < 16; ++j)
    xr[j] = xb[(size_t)(cg * 16 + j) * 16384 + ps];

  for (int k = 0; k < 8; ++k) {
    const int bk = k & 1;
#pragma unroll
    for (int a = 0; a < 4; ++a) {
      s16x4 hv, lv;
#pragma unroll
      for (int j = 0; j < 4; ++j) {
        const float v = xr[a * 4 + j];
        const unsigned short hb = f2bf(v);
        hv[j] = (short)hb;
        lv[j] = (short)f2bf(v - bf2f(hb));
      }
      *(s16x4*)&lds[bk][0][ps][cg * 16 + a * 4] = hv;
      *(s16x4*)&lds[bk][1][ps][cg * 16 + a * 4] = lv;
    }
    __syncthreads();

    if (k < 7) {
#pragma unroll
      for (int j = 0; j < 16; ++j)
        xr[j] = xb[(size_t)((k + 1) * 32 + cg * 16 + j) * 16384 + ps];
    }

    s16x8 Ah[4], Al[4];
    const int coff = lg << 3;
#pragma unroll
    for (int pf = 0; pf < 4; ++pf) {
      const int row = wp * 64 + pf * 16 + l15;
      s16x4 h0 = *(const s16x4*)&lds[bk][0][row][coff];
      s16x4 h1 = *(const s16x4*)&lds[bk][0][row][coff + 4];
      s16x4 l0 = *(const s16x4*)&lds[bk][1][row][coff];
      s16x4 l1 = *(const s16x4*)&lds[bk][1][row][coff + 4];
      Ah[pf] = __builtin_shufflevector(h0, h1, 0, 1, 2, 3, 4, 5, 6, 7);
      Al[pf] = __builtin_shufflevector(l0, l1, 0, 1, 2, 3, 4, 5, 6, 7);
    }

    const short* wh = whiF + ((size_t)(k * 16 + wo * 8) * 64 + lane) * 8;
    const short* wl = wloF + ((size_t)(k * 16 + wo * 8) * 64 + lane) * 8;
    s16x8 Bh = *(const s16x8*)wh;
    s16x8 Bl = *(const s16x8*)wl;
#pragma unroll
    for (int of = 0; of < 8; ++of) {
      s16x8 nBh = Bh, nBl = Bl;
      if (of < 7) {
        nBh = *(const s16x8*)(wh + (size_t)(of + 1) * 512);
        nBl = *(const s16x8*)(wl + (size_t)(of + 1) * 512);
      }
#pragma unroll
      for (int pf = 0; pf < 4; ++pf) {
        acc[pf][of] = __builtin_amdgcn_mfma_f32_16x16x32_bf16(Ah[pf], Bh, acc[pf][of], 0, 0, 0);
        acc[pf][of] = __builtin_amdgcn_mfma_f32_16x16x32_bf16(Ah[pf], Bl, acc[pf][of], 0, 0, 0);
        acc[pf][of] = __builtin_amdgcn_mfma_f32_16x16x32_bf16(Al[pf], Bh, acc[pf][of], 0, 0, 0);
      }
      Bh = nBh; Bl = nBl;
    }
  }

  float* fb = f1 + ((size_t)b << 22) + hw0;
  const int prow = wp * 64 + (lg << 2);
#pragma unroll
  for (int of = 0; of < 8; ++of) {
    const int o = wo * 128 + of * 16 + l15;
    float* fo = fb + ((size_t)o << 14);
#pragma unroll
    for (int pf = 0; pf < 4; ++pf)
      *(f32x4*)(fo + prow + pf * 16) = acc[pf][of];
  }
}

// ---------------------------------------------------------------------------
// Kernel 2: partial L1 distances (UNCHANGED -- control; its true duration
// should surface in top-5 once k_agg2 drops).
// ---------------------------------------------------------------------------
__global__ __launch_bounds__(256) void k_dist(const float* __restrict__ f1,
                                              float* __restrict__ dist_part)
{
  const int t    = threadIdx.x;
  const int r    = t >> 5, cq = t & 31;
  const int lane = t & 63;
  const int h0 = blockIdx.x * 8;
  const int b  = blockIdx.y;
  const int c0 = blockIdx.z * 32;
  const int h  = h0 + r;
  const int hu = h == 0 ? 0 : h - 1;
  const int hd = h == 127 ? 127 : h + 1;
  const int colo = cq * 4;
  const float* plane0 = f1 + ((size_t)(b * 256 + c0)) * 16384;

  float acc[4][8];
#pragma unroll
  for (int i = 0; i < 4; ++i)
#pragma unroll
    for (int k = 0; k < 8; ++k) acc[i][k] = 0.f;

#pragma unroll 4
  for (int cc = 0; cc < 32; ++cc) {
    const float* pl = plane0 + (size_t)cc * 16384;
    float4 vv[3];
    vv[0] = *(const float4*)(pl + hu * 128 + colo);
    vv[1] = *(const float4*)(pl + h  * 128 + colo);
    vv[2] = *(const float4*)(pl + hd * 128 + colo);
    float vals[3][6];
#pragma unroll
    for (int d = 0; d < 3; ++d) {
      const float lf = __shfl(vv[d].w, (lane + 63) & 63, 64);
      const float rg = __shfl(vv[d].x, (lane + 1) & 63, 64);
      vals[d][0] = (cq == 0)  ? vv[d].x : lf;
      vals[d][1] = vv[d].x; vals[d][2] = vv[d].y;
      vals[d][3] = vv[d].z; vals[d][4] = vv[d].w;
      vals[d][5] = (cq == 31) ? vv[d].w : rg;
    }
#pragma unroll
    for (int i = 0; i < 4; ++i) {
      const float cv = vals[1][i + 1];
      acc[i][0] += fabsf(cv - vals[0][i]);
      acc[i][1] += fabsf(cv - vals[0][i + 1]);
      acc[i][2] += fabsf(cv - vals[0][i + 2]);
      acc[i][3] += fabsf(cv - vals[1][i]);
      acc[i][4] += fabsf(cv - vals[1][i + 2]);
      acc[i][5] += fabsf(cv - vals[2][i]);
      acc[i][6] += fabsf(cv - vals[2][i + 1]);
      acc[i][7] += fabsf(cv - vals[2][i + 2]);
    }
  }

  const int p = (b << 14) + h * 128 + colo;
  float* base = dist_part + ((size_t)blockIdx.z << 19);   // chunk * 8*65536
#pragma unroll
  for (int k = 0; k < 8; ++k) {
    float4 v; v.x = acc[0][k]; v.y = acc[1][k]; v.z = acc[2][k]; v.w = acc[3][k];
    *(float4*)(base + (size_t)k * 65536 + p) = v;
  }
}

// ---------------------------------------------------------------------------
// Kernel 2b: sum the 8 chunk-partials per pixel, softmax once, write wts[p][8].
// ---------------------------------------------------------------------------
__global__ __launch_bounds__(256) void k_soft(const float* __restrict__ dist_part,
                                              const float* __restrict__ rp,
                                              float* __restrict__ wts)
{
  const int p = blockIdx.x * 256 + threadIdx.x;
  const float rv = rp[0];
  float d[8];
#pragma unroll
  for (int k = 0; k < 8; ++k) d[k] = 0.f;
  for (int ch = 0; ch < 8; ++ch) {
    const float* base = dist_part + ((size_t)ch << 19);
#pragma unroll
    for (int k = 0; k < 8; ++k) d[k] += base[(size_t)k * 65536 + p];
  }
  float lg[8];
  float mx = -rv * d[0];
#pragma unroll
  for (int k = 1; k < 8; ++k) mx = fmaxf(mx, -rv * d[k]);
  float sm = 0.f;
#pragma unroll
  for (int k = 0; k < 8; ++k) { lg[k] = __expf(fmaf(-rv, d[k], -mx)); sm += lg[k]; }
  const float inv = 1.f / sm;
  float4 w0, w1;
  w0.x = lg[0] * inv; w0.y = lg[1] * inv; w0.z = lg[2] * inv; w0.w = lg[3] * inv;
  w1.x = lg[4] * inv; w1.y = lg[5] * inv; w1.z = lg[6] * inv; w1.w = lg[7] * inv;
  *(float4*)(wts + (size_t)p * 8)     = w0;
  *(float4*)(wts + (size_t)p * 8 + 4) = w1;
}

// ---------------------------------------------------------------------------
// Kernel 3: weighted aggregation + residual + fused BN stats.
// R10 (ledger: R6 occupancy FAIL, R7 shuffle-removal FAIL, R9 LDS-staging
// ~null 116->111. Invariant: ~4100 cyc/channel-iter, VALUxdur constant.
// Last untouched per-iter cost: 256 waves atomicAdd the SAME two dwords
// s1[ch]/s2[ch], and the barrier's vmcnt(0) forces each wave to wait for
// its contended atomic to retire -> ~2.5-5K cyc RMW queue, matches):
//  * NO atomics: lane0 writes wave partials to LDS red[4][32]; after the
//    loop, wave 0 sums 4 waves and stores ONE coalesced partial per channel
//    to part_s/part_q[contrib64][ch256] (128KB each). k_stats reduces.
//  * staging/butterfly/grid: R9 structure unchanged.
// ---------------------------------------------------------------------------
__global__ __launch_bounds__(256, 2) void k_agg2(const float* __restrict__ f1,
                                                 const float* __restrict__ x,
                                                 const float* __restrict__ wts,
                                                 float* __restrict__ bn_in,
                                                 float* __restrict__ part_s,
                                                 float* __restrict__ part_q)
{
  __shared__ float tile[2][10][128];     // [dbuf][row][col] 10 KB
  __shared__ float red_s[4][32];
  __shared__ float red_q[4][32];
  const int t    = threadIdx.x;
  const int r    = t >> 5, cq = t & 31;
  const int lane = t & 63;
  const int wid  = t >> 6;
  const int h0 = blockIdx.x * 8;
  const int b  = blockIdx.y;
  const int c0 = blockIdx.z * 32;
  const int h  = h0 + r;
  const int colo = cq * 4;
  const int lidx = (cq == 0)  ? 0   : colo - 1;   // clamped left col
  const int ridx = (cq == 31) ? 127 : colo + 4;   // clamped right col
  const int p  = (b << 14) + h * 128 + colo;

  // staging map: float4 idx in [0,320): row=idx>>5 (0..9), col4=idx&31
  const int si0 = t;                   // all threads
  const int si1 = 256 + t;             // threads 0..63 only
  const int sr0 = si0 >> 5, sc0_ = si0 & 31;
  const int sr1 = si1 >> 5, sc1_ = si1 & 31;
  const int gr0 = min(max(h0 - 1 + sr0, 0), 127);
  const int gr1 = min(max(h0 - 1 + sr1, 0), 127);

  float m[4][8];
#pragma unroll
  for (int i = 0; i < 4; ++i) {
    float4 w0 = *(const float4*)(wts + (size_t)(p + i) * 8);
    float4 w1 = *(const float4*)(wts + (size_t)(p + i) * 8 + 4);
    m[i][0] = w0.x; m[i][1] = w0.y; m[i][2] = w0.z; m[i][3] = w0.w;
    m[i][4] = w1.x; m[i][5] = w1.y; m[i][6] = w1.z; m[i][7] = w1.w;
  }

  const float* plane0 = f1 + ((size_t)(b * 256 + c0)) * 16384;

  // prologue: stage channel 0 into buf 0
  {
    const float* pl = plane0;
    float4 a0 = *(const float4*)(pl + gr0 * 128 + sc0_ * 4);
    *(float4*)&tile[0][sr0][sc0_ * 4] = a0;
    if (t < 64) {
      float4 a1 = *(const float4*)(pl + gr1 * 128 + sc1_ * 4);
      *(float4*)&tile[0][sr1][sc1_ * 4] = a1;
    }
  }
  __syncthreads();

  for (int cc = 0; cc < 32; ++cc) {
    const int cur = cc & 1, nxt = cur ^ 1;

    // ---- issue staging loads for cc+1 EARLY (hide under compute) ----
    float4 a0n, a1n;
    if (cc < 31) {
      const float* pln = plane0 + (size_t)(cc + 1) * 16384;
      a0n = *(const float4*)(pln + gr0 * 128 + sc0_ * 4);
      if (t < 64) a1n = *(const float4*)(pln + gr1 * 128 + sc1_ * 4);
    }

    // ---- stencil from LDS: center row r+1, up r, down r+2 ----
    float vals[3][6];
#pragma unroll
    for (int d = 0; d < 3; ++d) {
      const float* row = &tile[cur][r + d][0];
      float4 c4 = *(const float4*)(row + colo);
      vals[d][0] = row[lidx];
      vals[d][1] = c4.x; vals[d][2] = c4.y;
      vals[d][3] = c4.z; vals[d][4] = c4.w;
      vals[d][5] = row[ridx];
    }

    const size_t chanoff = ((size_t)(b * 256 + c0 + cc)) * 16384 +
                           (size_t)h * 128 + colo;
    const float4 xv = *(const float4*)(x + chanoff);
    float o_[4] = {xv.x, xv.y, xv.z, xv.w};
#pragma unroll
    for (int i = 0; i < 4; ++i) {
      o_[i] = fmaf(m[i][0], vals[0][i],     o_[i]);
      o_[i] = fmaf(m[i][1], vals[0][i + 1], o_[i]);
      o_[i] = fmaf(m[i][2], vals[0][i + 2], o_[i]);
      o_[i] = fmaf(m[i][3], vals[1][i],     o_[i]);
      o_[i] = fmaf(m[i][4], vals[1][i + 2], o_[i]);
      o_[i] = fmaf(m[i][5], vals[2][i],     o_[i]);
      o_[i] = fmaf(m[i][6], vals[2][i + 1], o_[i]);
      o_[i] = fmaf(m[i][7], vals[2][i + 2], o_[i]);
    }
    float4 ov; ov.x = o_[0]; ov.y = o_[1]; ov.z = o_[2]; ov.w = o_[3];
    *(float4*)(bn_in + chanoff) = ov;

    float s = o_[0] + o_[1] + o_[2] + o_[3];
    float q = o_[0] * o_[0] + o_[1] * o_[1] + o_[2] * o_[2] + o_[3] * o_[3];
#pragma unroll
    for (int msk = 1; msk < 64; msk <<= 1) {
      s += __shfl_xor(s, msk, 64);
      q += __shfl_xor(q, msk, 64);
    }
    if (lane == 0) {
      red_s[wid][cc] = s;     // LDS, no global atomic
      red_q[wid][cc] = q;
    }

    // ---- write staged regs, one barrier per channel ----
    if (cc < 31) {
      *(float4*)&tile[nxt][sr0][sc0_ * 4] = a0n;
      if (t < 64) *(float4*)&tile[nxt][sr1][sc1_ * 4] = a1n;
    }
    __syncthreads();
  }

  // final loop barrier makes red_* visible; wave 0 reduces + stores
  if (t < 32) {
    const int contrib = blockIdx.x * 4 + blockIdx.y;      // 0..63
    float s4 = red_s[0][t] + red_s[1][t] + red_s[2][t] + red_s[3][t];
    float q4 = red_q[0][t] + red_q[1][t] + red_q[2][t] + red_q[3][t];
    part_s[contrib * 256 + c0 + t] = s4;
    part_q[contrib * 256 + c0 + t] = q4;
  }
}

// ---------------------------------------------------------------------------
// Kernel 4: BN folds (now reduces 64 per-block partials per channel)
// ---------------------------------------------------------------------------
__global__ void k_stats(const float* __restrict__ part_s, const float* __restrict__ part_q,
                        const float* __restrict__ gamma, const float* __restrict__ beta,
                        float* __restrict__ scale, float* __restrict__ shift)
{
  const int c = threadIdx.x;
  float s = 0.f, q = 0.f;
#pragma unroll 8
  for (int k = 0; k < 64; ++k) {
    s += part_s[k * 256 + c];   // consecutive lanes -> consecutive addrs
    q += part_q[k * 256 + c];
  }
  const float n = 65536.f;
  const float mean = s / n;
  const float var  = q / n - mean * mean;
  const float sc   = gamma[c] * rsqrtf(var + EPS_);
  scale[c] = sc;
  shift[c] = beta[c] - mean * sc;
}

// ---------------------------------------------------------------------------
// Kernel 5: elementwise BN affine + LeakyReLU
// ---------------------------------------------------------------------------
__global__ __launch_bounds__(256) void k_apply(const float* __restrict__ bn_in,
                                               const float* __restrict__ scale,
                                               const float* __restrict__ shift,
                                               float* __restrict__ out)
{
  const int base = blockIdx.x * 1024 + threadIdx.x;   // float4 index
#pragma unroll
  for (int j = 0; j < 4; ++j) {
    const int idx = base + j * 256;
    const int c   = (idx >> 12) & 255;
    const float sc = scale[c], sh = shift[c];
    const float4 v = *(const float4*)(bn_in + (size_t)idx * 4);
    float4 o;
    float u;
    u = fmaf(v.x, sc, sh); o.x = u > 0.f ? u : 0.01f * u;
    u = fmaf(v.y, sc, sh); o.y = u > 0.f ? u : 0.01f * u;
    u = fmaf(v.z, sc, sh); o.z = u > 0.f ? u : 0.01f * u;
    u = fmaf(v.w, sc, sh); o.w = u > 0.f ? u : 0.01f * u;
    *(float4*)(out + (size_t)idx * 4) = o;
  }
}

// ---------------------------------------------------------------------------
// Workspace: f1 64MB | bn_in 64MB (dist_part 16MB aliases its head; wfrag
// 256KB parks at bn_in+32MB -- dead before k_agg2 writes) | wts 2MB |
// scale/shift 2KB | part_s/part_q 128KB.  Total ~130.13MB.
// ---------------------------------------------------------------------------
extern "C" void kernel_launch(void* const* d_in, const int* in_sizes, int n_in,
                              void* d_out, int out_size, void* d_ws, size_t ws_size,
                              hipStream_t stream)
{
  const float* x     = (const float*)d_in[0];
  const float* W1    = (const float*)d_in[1];
  const float* b1    = (const float*)d_in[2];
  const float* r     = (const float*)d_in[3];
  const float* gamma = (const float*)d_in[4];
  const float* beta  = (const float*)d_in[5];
  float* out = (float*)d_out;

  char* ws = (char*)d_ws;
  float* f1        = (float*)ws;                           // 64 MB
  float* bn_in     = (float*)(ws + ((size_t)64 << 20));    // 64 MB
  float* dist_part = bn_in;                                // 16 MB alias (dead before bn_in written)
  short* whiF      = (short*)(ws + ((size_t)96 << 20));    // 128 KB (inside bn_in, dead region)
  short* wloF      = whiF + 65536;                         // 128 KB
  float* wts       = (float*)(ws + ((size_t)128 << 20));   // 2 MB
  float* scale     = wts + 524288;
  float* shift     = scale + 256;
  float* part_s    = shift + 256;                          // 64 KB
  float* part_q    = part_s + 16384;                       // 64 KB

  k_wprep<<<dim3(32),        256, 0, stream>>>(W1, whiF, wloF);
  k_mm   <<<dim3(128, 4),    256, 0, stream>>>(x, whiF, wloF, b1, f1);
  k_dist <<<dim3(16, 4, 8),  256, 0, stream>>>(f1, dist_part);
  k_soft <<<dim3(256),       256, 0, stream>>>(dist_part, r, wts);
  k_agg2 <<<dim3(16, 4, 8),  256, 0, stream>>>(f1, x, wts, bn_in, part_s, part_q);
  k_stats<<<dim3(1),         256, 0, stream>>>(part_s, part_q, gamma, beta, scale, shift);
  k_apply<<<dim3(4096),      256, 0, stream>>>(bn_in, scale, shift, out);
}